// Round 9
// baseline (6092.828 us; speedup 1.0000x reference)
//
#include <hip/hip_runtime.h>
#include <stdint.h>

typedef unsigned int u32;
typedef unsigned short u16;

#define TT 256

// ---- weight layout: row-major, 16B-aligned K-sections ----
// LSTM row (272 words = 544 slots): [xt 16 slots][i0: h0..h215][i1: h216..h358+pad][i2: h359..h511+pads]
// L0 row   (120 words): [xt 16 slots][hl0..hl215] (116 real words)
// L1 row   (192 words): [i0 216][hl216..358][pads]          (r8 layout, unchanged)
// L2 row   (160 words): [i1 143+pad][(h358*0,h359)|h360..][pads] (r8 layout, unchanged)
#define LSW 272
#define B0W 120
#define C1W 192
#define D2W 160
#define OFF_L0  (2048*LSW)              // 557056
#define OFF_L1  (OFF_L0 + 864*B0W)      // 660736
#define OFF_L2  (OFF_L1 + 576*C1W)      // 771328
#define OFF_HL  (OFF_L2 + 640*D2W)      // 873728  h_lstm exchange [128][264] u32 (u16[528])
#define OFF_REC (OFF_HL + 128*264)      // 907520  h_rec  exchange [128][264] u32
#define OFF_SYNC (OFF_REC + 128*264)    // 941312  flags [32 quads][8 slices][16]
#define WS_TOTAL (OFF_SYNC + 4096)      // 945408 u32 ~= 3.61 MiB
#define NFL 16

__device__ __forceinline__ u16 f2bf(float f){
  u32 u = __builtin_bit_cast(u32, f);
  u += 0x7FFFu + ((u >> 16) & 1u);      // RNE
  return (u16)(u >> 16);
}
__device__ __forceinline__ u32 packbf(float lo, float hi){
  return (u32)f2bf(lo) | ((u32)f2bf(hi) << 16);
}
__device__ __forceinline__ float bdot(u32 a, u32 b, float c){
  float d;
  asm("v_dot2_f32_bf16 %0, %1, %2, %3" : "=v"(d) : "v"(a), "v"(b), "v"(c));
  return d;
}
__device__ __forceinline__ float sigm(float x){ return 1.0f/(1.0f + __expf(-x)); }
__device__ __forceinline__ float tanh_(float x){ return 1.0f - 2.0f/(1.0f + __expf(2.0f*x)); }

__device__ __forceinline__ u32 xload(const u32* p){
  return __hip_atomic_load(p, __ATOMIC_RELAXED, __HIP_MEMORY_SCOPE_AGENT);
}
__device__ __forceinline__ void xstore16(u16* p, u16 v){
  __hip_atomic_store(p, v, __ATOMIC_RELAXED, __HIP_MEMORY_SCOPE_AGENT);
}

// Flag barrier (r8-proven): monotonic per-(quad,slice) flag, no RMW.
__device__ __forceinline__ void bar_arrive(u32* fl, int s, u32 v){
  __syncthreads();
  if (threadIdx.x == 0)
    __hip_atomic_store(&fl[s*NFL], v, __ATOMIC_RELAXED, __HIP_MEMORY_SCOPE_AGENT);
}
__device__ __forceinline__ void bar_wait(const u32* fl, u32 v){
  if (threadIdx.x < 8){
    int guard = 1 << 16;
    while (__hip_atomic_load(&fl[threadIdx.x*NFL], __ATOMIC_RELAXED, __HIP_MEMORY_SCOPE_AGENT) < v
           && --guard) __builtin_amdgcn_s_sleep(1);
  }
  __syncthreads();
  asm volatile("" ::: "memory");
}

// section-aligned partial dot
template<int G0, int G1>
__device__ __forceinline__ float dotg(const u32* wrow, const u32* xc, float A){
  #pragma unroll
  for (int g = G0; g < G1; ++g){
    uint4 wv = *(const uint4*)(wrow + (g<<2));
    uint4 av = *(const uint4*)(xc + (g<<2));
    A=bdot(wv.x,av.x,A); A=bdot(wv.y,av.y,A); A=bdot(wv.z,av.z,A); A=bdot(wv.w,av.w,A);
  }
  return A;
}

// ---------------- weight value mappings ----------------
__device__ __forceinline__ float lstmval(const float* wi, const float* wr, int r, int s){
  if (s < 9)   return wi[r*9 + s];
  if (s < 16)  return 0.f;
  if (s < 375) return wr[r*512 + (s-16)];    // i0|i1 sections: h0..h358
  if (s == 375) return 0.f;
  if (s < 529) return wr[r*512 + (s-17)];    // i2 section: h359..h511
  return 0.f;
}
__device__ __forceinline__ float l0val(const float* W, const int* M, int o, int k){
  int ki;
  if (k < 9) ki = k;
  else if (k >= 16 && k < 232) ki = 9 + (k - 16);
  else return 0.f;
  float w = W[o*225 + ki];
  if (M) w *= (float)M[o*225 + ki];
  return w;
}
__device__ __forceinline__ float l1val(const float* W, const int* M, int o, int k){
  if (k >= 359) return 0.f;
  float w = W[o*359 + k];
  if (M) w *= (float)M[o*359 + k];
  return w;
}
__device__ __forceinline__ float l2val(const float* W, const int* M, int o, int k){
  if (k == 143 || k == 144 || k >= 298) return 0.f;
  int ki = (k < 143) ? k : k - 2;
  float w = W[o*296 + ki];
  if (M) w *= (float)M[o*296 + ki];
  return w;
}

__global__ void prep_kernel(
    const float* __restrict__ wi, const float* __restrict__ wr,
    const float* __restrict__ w10,const float* __restrict__ w20,const float* __restrict__ wa0,const float* __restrict__ wb0,const int* __restrict__ m0,
    const float* __restrict__ w11,const float* __restrict__ w21,const float* __restrict__ wa1,const float* __restrict__ wb1,const int* __restrict__ m1,
    const float* __restrict__ w12,const float* __restrict__ w22,const float* __restrict__ wa2,const float* __restrict__ wb2,const int* __restrict__ m2,
    u32* __restrict__ ws)
{
  for (int i = blockIdx.x*blockDim.x + threadIdx.x; i < WS_TOTAL; i += gridDim.x*blockDim.x){
    float lo = 0.f, hi = 0.f;
    if (i < OFF_L0){
      int row = i / LSW, k2 = i - row*LSW;
      int orig = (row >> 2) + ((row & 3) << 9);   // gate-interleaved: row = 4v+g
      lo = lstmval(wi, wr, orig, 2*k2);
      hi = lstmval(wi, wr, orig, 2*k2+1);
    } else if (i < OFF_L1){
      int loc = i - OFF_L0;
      int row = loc / B0W, k2 = loc - row*B0W;
      int o = row >> 2, m = row & 3;
      const float* W = (m==0)?w10:(m==1)?w20:(m==2)?wa0:wb0;
      const int* M = (m < 2) ? m0 : nullptr;
      lo = l0val(W, M, o, 2*k2); hi = l0val(W, M, o, 2*k2+1);
    } else if (i < OFF_L2){
      int loc = i - OFF_L1;
      int row = loc / C1W, k2 = loc - row*C1W;
      int o = row >> 2, m = row & 3;
      if (o < 143){
        const float* W = (m==0)?w11:(m==1)?w21:(m==2)?wa1:wb1;
        const int* M = (m < 2) ? m1 : nullptr;
        lo = l1val(W, M, o, 2*k2); hi = l1val(W, M, o, 2*k2+1);
      }
    } else if (i < OFF_HL){
      int loc = i - OFF_L2;
      int row = loc / D2W, k2 = loc - row*D2W;
      int o = row >> 2, m = row & 3;
      if (o < 153){
        const float* W = (m==0)?w12:(m==1)?w22:(m==2)?wa2:wb2;
        const int* M = (m < 2) ? m2 : nullptr;
        lo = l2val(W, M, o, 2*k2); hi = l2val(W, M, o, 2*k2+1);
      }
    } else {
      ws[i] = 0u;                 // exchange arrays + flags
      continue;
    }
    ws[i] = packbf(lo, hi);
  }
}

// ---------------- split-K pipelined sliced persistent kernel ----------------
// grid 256 = 8 slices x 32 quads; slice s = bid&7 (-> XCD s, perf-only), quad
// owns 4 batches. thread: b4 = tid&3, rr = tid>>2; lanes 0-3 share weight rows.
// Per step: the bulk partial dots (A_xt/A_i0/A_i1, C_hl, D_hl) execute inside
// the barrier-wait shadows; only C_i0, D_i1, A_i2, B remain on the sync chain.
__global__ __launch_bounds__(1024) void liquid_rnn(
    const float* __restrict__ x, const float* __restrict__ dtp,
    const float* __restrict__ lstm_bi,
    const float* __restrict__ b10, const float* __restrict__ b20,
    const float* __restrict__ ba0, const float* __restrict__ bb0,
    const float* __restrict__ b11, const float* __restrict__ b21,
    const float* __restrict__ ba1, const float* __restrict__ bb1,
    const float* __restrict__ b12, const float* __restrict__ b22,
    const float* __restrict__ ba2, const float* __restrict__ bb2,
    u32* __restrict__ ws, float* __restrict__ out)
{
  __shared__ u32 xcA[4][272];   // LSTM xc: [xt 8w][i0 108w][i1 72w][i2 80w][pad]
  __shared__ u32 xcB[4][120];   // L0 xc:   [xt 8w][hl0:216 108w][pad]
  __shared__ u32 xcC[4][192];   // L1 xc:   [i0 108w][hl216:359 72w][pad]
  __shared__ u32 xcD[4][160];   // L2 xc:   [i1 72w][hl-tail 77w][pad]

  const int tid  = threadIdx.x;
  const int bid  = blockIdx.x;
  const int s    = bid & 7;
  const int quad = bid >> 3;
  const int b4   = tid & 3;
  const int rr   = tid >> 2;
  const int batch= quad*4 + b4;

  u32* hlw  = ws + OFF_HL;
  u32* recw = ws + OFF_REC;
  u16* hl16 = (u16*)hlw;
  u16* rec16= (u16*)recw;
  u32* fl   = ws + OFF_SYNC + quad*(8*NFL);

  // hoisted constants
  const int vA = s*64 + (rr >> 2);
  const float lb = lstm_bi[vA + 512*(rr & 3)];
  int oB = 0; float biasB = 0.f;
  if (tid < 432){ int m = rr & 3; oB = 27*s + (rr >> 2);
    biasB = ((m==0)?b10:(m==1)?b20:(m==2)?ba0:bb0)[oB]; }
  int oC = 0; float biasC = 0.f;
  if (tid < 288){ int m = rr & 3; oC = 18*s + (rr >> 2);
    if (oC < 143) biasC = ((m==0)?b11:(m==1)?b21:(m==2)?ba1:bb1)[oC]; }
  int oD = 0; float biasD = 0.f;
  if (tid < 320){ int m = rr & 3; oD = 20*s + (rr >> 2);
    if (oD < 153) biasD = ((m==0)?b12:(m==1)?b22:(m==2)?ba2:bb2)[oD]; }

  const u32* wrA = ws + (size_t)(s*256 + rr)*LSW;
  const u32* wrB = ws + OFF_L0 + (size_t)(s*108 + (rr < 108 ? rr : 0))*B0W;
  const u32* wrC = ws + OFF_L1 + (size_t)(s*72  + (rr < 72  ? rr : 0))*C1W;
  const u32* wrD = ws + OFF_L2 + (size_t)(s*80  + (rr < 80  ? rr : 0))*D2W;

  // helpers for xt staging
  auto stage_xt = [&](u32 (*dst)[272], int tt, int idx){
    int bb = idx/5, w = idx - bb*5;
    int bg = quad*4 + bb;
    float e0, e1;
    if (w < 4){ e0 = x[((size_t)bg*TT + tt)*8 + 2*w]; e1 = x[((size_t)bg*TT + tt)*8 + 2*w+1]; }
    else      { e0 = dtp[(size_t)bg*TT + tt]; e1 = 0.f; }
    dst[bb][w] = packbf(e0, e1);
  };
  auto stage_xtB = [&](int tt, int idx){
    int bb = idx/5, w = idx - bb*5;
    int bg = quad*4 + bb;
    float e0, e1;
    if (w < 4){ e0 = x[((size_t)bg*TT + tt)*8 + 2*w]; e1 = x[((size_t)bg*TT + tt)*8 + 2*w+1]; }
    else      { e0 = dtp[(size_t)bg*TT + tt]; e1 = 0.f; }
    xcB[bb][w] = packbf(e0, e1);
  };

  // init LDS
  for (int i = tid; i < 4*272; i += 1024) ((u32*)xcA)[i] = 0u;
  for (int i = tid; i < 4*120; i += 1024) ((u32*)xcB)[i] = 0u;
  for (int i = tid; i < 4*192; i += 1024) ((u32*)xcC)[i] = 0u;
  for (int i = tid; i < 4*160; i += 1024) ((u32*)xcD)[i] = 0u;
  float creg = 0.f;
  float accA = lb, accC = biasC, accD = biasD;
  __syncthreads();
  if (tid < 20){ stage_xt(xcA, 0, tid); stage_xtB(0, tid); }
  __syncthreads();

  // ---------- prologue: LSTM(0) from xt only (h_rec(0)=0), then B(0) ----------
  {
    accA = dotg<0,2>(wrA, xcA[b4], accA);
    float zig = __shfl_down(accA, 4), zfg = __shfl_down(accA, 8), zog = __shfl_down(accA, 12);
    if (!(rr & 3)){
      creg = creg * sigm(zfg + 1.0f) + tanh_(accA) * sigm(zig);
      float hl = tanh_(creg) * sigm(zog);
      xstore16(&hl16[(size_t)batch*528 + vA], f2bf(hl));
    }
    accA = lb;
  }
  bar_arrive(fl, s, 1);
  bar_wait(fl, 1);
  { // stage hl(1)
    int bb = tid >> 8, w = tid & 255;
    u32 v = xload(&hlw[(size_t)(quad*4+bb)*264 + w]);
    if (w < 108) xcB[bb][8+w] = v;
    else if (w < 180){ xcC[bb][w] = v; if (w == 179) xcD[bb][72] = v; }
    else xcD[bb][w-107] = v;
  }
  __syncthreads();
  if (tid < 432){ // B(0)
    float A0 = dotg<0,30>(wrB, xcB[b4], biasB);
    float A1 = __shfl_down(A0, 4), A2 = __shfl_down(A0, 8), A3 = __shfl_down(A0, 12);
    if (!(rr & 3)){
      float ti = sigm(A3 - A2);
      float o0 = tanh_(A0)*(1.f - ti) + ti*tanh_(A1);
      xstore16(&rec16[(size_t)batch*528 + oB], f2bf(o0));
    }
  }
  bar_arrive(fl, s, 2);
  if (tid < 20) stage_xt(xcA, 1, tid);   // xt(1) for LSTM(1)'s A_xt (read after bar_wait(2))

  // ---------- main loop ----------
  for (int k = 0; k < TT; ++k){
    const u32 fb = 4u*(u32)k;
    // shadows: C_hl(k), D_hl(k)  (hl(k+1) staged previously)
    if (tid < 288) accC = dotg<27,48>(wrC, xcC[b4], accC);
    if (tid < 320) accD = dotg<18,40>(wrD, xcD[b4], accD);
    bar_wait(fl, fb+2);                        // i0_k ready
    if (tid < 432){                            // stage i0_k
      int bb = tid/108, j = tid - bb*108;
      u32 v = xload(&recw[(size_t)(quad*4+bb)*264 + j]);
      xcA[bb][8+j] = v; xcC[bb][j] = v;
    } else if (tid < 452 && k+1 < TT){
      stage_xtB(k+1, tid-432);                 // xt(k+1) for B(k+1)
    }
    __syncthreads();
    if (tid < 288){                            // C(k) finish
      float A0 = dotg<0,27>(wrC, xcC[b4], accC);
      float A1 = __shfl_down(A0, 4), A2 = __shfl_down(A0, 8), A3 = __shfl_down(A0, 12);
      if (!(rr & 3) && oC < 143){
        float ti = sigm(A3 - A2);
        float o0 = tanh_(A0)*(1.f - ti) + ti*tanh_(A1);
        xstore16(&rec16[(size_t)batch*528 + 216 + oC], f2bf(o0));
        if (k == TT-1) out[(size_t)batch*512 + 216 + oC] = o0;
      }
      accC = biasC;
    }
    bar_arrive(fl, s, fb+3);                   // publish i1_k
    accA = dotg<0,29>(wrA, xcA[b4], accA);     // shadow: A_xt + A_i0
    bar_wait(fl, fb+3);                        // i1_k ready
    if (tid < 288){                            // stage i1_k
      int bb = tid/72, j = tid - bb*72;
      u32 v = xload(&recw[(size_t)(quad*4+bb)*264 + 108 + j]);
      xcA[bb][116+j] = v; xcD[bb][j] = v;
    }
    __syncthreads();
    if (tid < 320){                            // D(k) finish
      float A0 = dotg<0,18>(wrD, xcD[b4], accD);
      float A1 = __shfl_down(A0, 4), A2 = __shfl_down(A0, 8), A3 = __shfl_down(A0, 12);
      if (!(rr & 3) && oD < 153){
        float ti = sigm(A3 - A2);
        float o0 = tanh_(A0)*(1.f - ti) + ti*tanh_(A1);
        xstore16(&rec16[(size_t)batch*528 + 360 + oD], f2bf(o0));
        if (k == TT-1) out[(size_t)batch*512 + 359 + oD] = o0;
      }
      accD = biasD;
    }
    bar_arrive(fl, s, fb+4);                   // publish i2_k
    if (k == TT-1) break;
    accA = dotg<29,47>(wrA, xcA[b4], accA);    // shadow: A_i1
    bar_wait(fl, fb+4);                        // i2_k ready
    if (tid < 308){                            // stage i2_k
      int bb = tid/77, j = tid - bb*77;
      xcA[bb][188+j] = xload(&recw[(size_t)(quad*4+bb)*264 + 180 + j]);
    } else if (tid < 328 && k+2 < TT){
      stage_xt(xcA, k+2, tid-308);             // xt(k+2) for next iter's A_xt
    }
    __syncthreads();
    {                                          // A(k+1) finish: i2 + pointwise
      accA = dotg<47,67>(wrA, xcA[b4], accA);
      float zig = __shfl_down(accA, 4), zfg = __shfl_down(accA, 8), zog = __shfl_down(accA, 12);
      if (!(rr & 3)){
        creg = creg * sigm(zfg + 1.0f) + tanh_(accA) * sigm(zig);
        float hl = tanh_(creg) * sigm(zog);
        xstore16(&hl16[(size_t)batch*528 + vA], f2bf(hl));
      }
      accA = lb;
    }
    bar_arrive(fl, s, fb+5);                   // publish hl(k+2)
    bar_wait(fl, fb+5);                        // hl(k+2) ready
    {                                          // stage hl(k+2)
      int bb = tid >> 8, w = tid & 255;
      u32 v = xload(&hlw[(size_t)(quad*4+bb)*264 + w]);
      if (w < 108) xcB[bb][8+w] = v;
      else if (w < 180){ xcC[bb][w] = v; if (w == 179) xcD[bb][72] = v; }
      else xcD[bb][w-107] = v;
    }
    __syncthreads();
    if (tid < 432){                            // B(k+1)
      float A0 = dotg<0,30>(wrB, xcB[b4], biasB);
      float A1 = __shfl_down(A0, 4), A2 = __shfl_down(A0, 8), A3 = __shfl_down(A0, 12);
      if (!(rr & 3)){
        float ti = sigm(A3 - A2);
        float o0 = tanh_(A0)*(1.f - ti) + ti*tanh_(A1);
        xstore16(&rec16[(size_t)batch*528 + oB], f2bf(o0));
        if (k+1 == TT-1) out[(size_t)batch*512 + oB] = o0;
      }
    }
    bar_arrive(fl, s, fb+6);                   // publish i0_{k+1}
  }

  if (!(rr & 3)) out[65536 + (size_t)batch*512 + vA] = creg;
}

extern "C" void kernel_launch(void* const* d_in, const int* in_sizes, int n_in,
                              void* d_out, int out_size, void* d_ws, size_t ws_size,
                              hipStream_t stream)
{
  (void)in_sizes; (void)n_in; (void)out_size; (void)ws_size;
  const float* x   = (const float*)d_in[0];
  const float* dt  = (const float*)d_in[1];
  const float* wi  = (const float*)d_in[2];
  const float* wr  = (const float*)d_in[3];
  const float* bi  = (const float*)d_in[4];
  const float* w10 = (const float*)d_in[5];  const float* b10 = (const float*)d_in[6];
  const float* w20 = (const float*)d_in[7];  const float* b20 = (const float*)d_in[8];
  const float* wa0 = (const float*)d_in[9];  const float* ba0 = (const float*)d_in[10];
  const float* wb0 = (const float*)d_in[11]; const float* bb0 = (const float*)d_in[12];
  const float* w11 = (const float*)d_in[13]; const float* b11 = (const float*)d_in[14];
  const float* w21 = (const float*)d_in[15]; const float* b21 = (const float*)d_in[16];
  const float* wa1 = (const float*)d_in[17]; const float* ba1 = (const float*)d_in[18];
  const float* wb1 = (const float*)d_in[19]; const float* bb1 = (const float*)d_in[20];
  const float* w12 = (const float*)d_in[21]; const float* b12 = (const float*)d_in[22];
  const float* w22 = (const float*)d_in[23]; const float* b22 = (const float*)d_in[24];
  const float* wa2 = (const float*)d_in[25]; const float* ba2 = (const float*)d_in[26];
  const float* wb2 = (const float*)d_in[27]; const float* bb2 = (const float*)d_in[28];
  const int* m0 = (const int*)d_in[29];
  const int* m1 = (const int*)d_in[30];
  const int* m2 = (const int*)d_in[31];

  u32* ws    = (u32*)d_ws;         // needs WS_TOTAL*4 ~= 3.61 MiB
  float* out = (float*)d_out;      // f32: h[128*512] then c[128*512]

  prep_kernel<<<dim3(924), dim3(1024), 0, stream>>>(
      wi, wr,
      w10,w20,wa0,wb0,m0,
      w11,w21,wa1,wb1,m1,
      w12,w22,wa2,wb2,m2,
      ws);

  liquid_rnn<<<dim3(256), dim3(1024), 0, stream>>>(
      x, dt, bi,
      b10,b20,ba0,bb0,
      b11,b21,ba1,bb1,
      b12,b22,ba2,bb2,
      ws, out);
}